// Round 1
// baseline (322.386 us; speedup 1.0000x reference)
//
#include <hip/hip_runtime.h>

#define B 8
#define F 16
#define K 24
#define L 147456            // 384*384
#define CHUNK 1024          // pixels per block (256 threads x 4 pixels)
#define NCHUNK (L / CHUNK)  // 144
#define EPSF 1e-8f
#define DELTA_VAR 0.5f
#define DELTA_DIST 1.5f
#define GAMMA 0.001f

// Workspace layout (bytes):
//   0      : sums    float[B][F][K]   (12288)
//   12288  : counts  float[B][K]      (768)
//   13056  : varsums float[B][K]      (768)
//   13824  : means   float[B][F][K]   (12288)  -> ends at 26112
//   26624  : labels  uint8[B][L]      (1179648) -> total ~1.18 MB
#define OFF_COUNTS 12288
#define OFF_VARS   13056
#define OFF_MEANS  13824
#define OFF_LABELS 26624

// ---------------- Kernel 1: segment sums + counts + label cache ----------------
__global__ __launch_bounds__(256) void k1_sums(const float* __restrict__ x,
                                               const float* __restrict__ t,
                                               float* __restrict__ sums,
                                               float* __restrict__ counts,
                                               unsigned char* __restrict__ labels) {
    // per-wave accumulators to cut LDS-atomic contention (4 waves/block)
    __shared__ float acc[4][F * 25];   // stride 25 to spread banks
    __shared__ float cnt[4][K];
    const int tid = threadIdx.x;
    const int w = tid >> 6;

    for (int i = tid; i < 4 * F * 25; i += 256) ((float*)acc)[i] = 0.f;
    for (int i = tid; i < 4 * K; i += 256) ((float*)cnt)[i] = 0.f;
    __syncthreads();

    const int b = blockIdx.x / NCHUNK;
    const int chunk = blockIdx.x % NCHUNK;
    const int l = chunk * CHUNK + tid * 4;

    // --- find labels for 4 consecutive pixels (t is exactly one-hot fp32) ---
    const float4* t4 = (const float4*)t;
    int lab0 = 0, lab1 = 0, lab2 = 0, lab3 = 0;
    #pragma unroll
    for (int c = 0; c < K; ++c) {
        float4 tv = t4[((size_t)(b * K + c) * L + l) >> 2];
        lab0 += c * (tv.x > 0.5f);
        lab1 += c * (tv.y > 0.5f);
        lab2 += c * (tv.z > 0.5f);
        lab3 += c * (tv.w > 0.5f);
    }

    // --- accumulate x into per-wave [f][label] sums ---
    const float4* x4 = (const float4*)x;
    float* a = acc[w];
    #pragma unroll
    for (int f = 0; f < F; ++f) {
        float4 xv = x4[((size_t)(b * F + f) * L + l) >> 2];
        atomicAdd(&a[f * 25 + lab0], xv.x);
        atomicAdd(&a[f * 25 + lab1], xv.y);
        atomicAdd(&a[f * 25 + lab2], xv.z);
        atomicAdd(&a[f * 25 + lab3], xv.w);
    }
    atomicAdd(&cnt[w][lab0], 1.f);
    atomicAdd(&cnt[w][lab1], 1.f);
    atomicAdd(&cnt[w][lab2], 1.f);
    atomicAdd(&cnt[w][lab3], 1.f);

    // cache labels for pass 2
    *(uchar4*)&labels[(size_t)b * L + l] =
        make_uchar4((unsigned char)lab0, (unsigned char)lab1,
                    (unsigned char)lab2, (unsigned char)lab3);

    __syncthreads();
    // block reduce 4 wave-copies -> global atomics (3264 distinct addresses total)
    for (int i = tid; i < F * K; i += 256) {
        int f = i / K, c = i % K;
        float v = acc[0][f * 25 + c] + acc[1][f * 25 + c] +
                  acc[2][f * 25 + c] + acc[3][f * 25 + c];
        atomicAdd(&sums[(b * F + f) * K + c], v);
    }
    for (int i = tid; i < K; i += 256) {
        float v = cnt[0][i] + cnt[1][i] + cnt[2][i] + cnt[3][i];
        atomicAdd(&counts[b * K + i], v);
    }
}

// ---------------- Kernel 2: finalize means ----------------
__global__ __launch_bounds__(256) void k2_means(const float* __restrict__ sums,
                                                const float* __restrict__ counts,
                                                const int* __restrict__ ncl,
                                                float* __restrict__ means) {
    int idx = blockIdx.x * 256 + threadIdx.x;
    if (idx >= B * F * K) return;
    int b = idx / (F * K);
    int c = idx % K;
    float valid = (c < ncl[b]) ? 1.f : 0.f;
    means[idx] = sums[idx] / (counts[b * K + c] + EPSF) * valid;
}

// ---------------- Kernel 3: per-pixel variance hinge, per-cluster sums ----------------
__global__ __launch_bounds__(256) void k3_var(const float* __restrict__ x,
                                              const unsigned char* __restrict__ labels,
                                              const float* __restrict__ means,
                                              float* __restrict__ varsums) {
    __shared__ float m[F * K];       // this batch's means
    __shared__ float vacc[4][K];
    const int tid = threadIdx.x;
    const int w = tid >> 6;
    const int b = blockIdx.x / NCHUNK;
    const int chunk = blockIdx.x % NCHUNK;

    for (int i = tid; i < F * K; i += 256) m[i] = means[b * F * K + i];
    for (int i = tid; i < 4 * K; i += 256) ((float*)vacc)[i] = 0.f;
    __syncthreads();

    const int l = chunk * CHUNK + tid * 4;
    uchar4 lv = *(const uchar4*)&labels[(size_t)b * L + l];
    const int lab0 = lv.x, lab1 = lv.y, lab2 = lv.z, lab3 = lv.w;

    float d0 = 0.f, d1 = 0.f, d2 = 0.f, d3 = 0.f;
    const float4* x4 = (const float4*)x;
    #pragma unroll
    for (int f = 0; f < F; ++f) {
        float4 xv = x4[((size_t)(b * F + f) * L + l) >> 2];
        float u0 = xv.x - m[f * K + lab0]; d0 += u0 * u0;
        float u1 = xv.y - m[f * K + lab1]; d1 += u1 * u1;
        float u2 = xv.z - m[f * K + lab2]; d2 += u2 * u2;
        float u3 = xv.w - m[f * K + lab3]; d3 += u3 * u3;
    }
    float s0 = fmaxf(sqrtf(d0) - DELTA_VAR, 0.f); s0 *= s0;
    float s1 = fmaxf(sqrtf(d1) - DELTA_VAR, 0.f); s1 *= s1;
    float s2 = fmaxf(sqrtf(d2) - DELTA_VAR, 0.f); s2 *= s2;
    float s3 = fmaxf(sqrtf(d3) - DELTA_VAR, 0.f); s3 *= s3;
    atomicAdd(&vacc[w][lab0], s0);
    atomicAdd(&vacc[w][lab1], s1);
    atomicAdd(&vacc[w][lab2], s2);
    atomicAdd(&vacc[w][lab3], s3);

    __syncthreads();
    for (int i = tid; i < K; i += 256) {
        float v = vacc[0][i] + vacc[1][i] + vacc[2][i] + vacc[3][i];
        atomicAdd(&varsums[b * K + i], v);
    }
}

// ---------------- Kernel 4: combine all three terms -> scalar ----------------
__global__ __launch_bounds__(256) void k4_final(const float* __restrict__ means,
                                                const float* __restrict__ counts,
                                                const float* __restrict__ varsums,
                                                const int* __restrict__ ncl,
                                                float* __restrict__ out) {
    __shared__ float red[256];
    const int tid = threadIdx.x;
    float total = 0.f;
    for (int idx = tid; idx < B * K * K; idx += 256) {
        int b = idx / (K * K);
        int r = idx % (K * K);
        int c = r / K;
        int d = r % K;
        int ncb = ncl[b];
        float fnc = (float)ncb;
        if (d == 0 && c < ncb && ncb > 0) {
            // variance term contribution for (b,c)
            float cv = varsums[b * K + c] / (counts[b * K + c] + EPSF);
            total += cv / (fnc + EPSF) * (1.0f / B);
            // regularization term
            float m2 = 0.f;
            #pragma unroll
            for (int f = 0; f < F; ++f) {
                float mv = means[(b * F + f) * K + c];
                m2 += mv * mv;
            }
            total += GAMMA * sqrtf(m2) / fnc * (1.0f / B);
        }
        if (c != d && c < ncb && d < ncb && ncb > 1) {
            float pd2 = 0.f;
            #pragma unroll
            for (int f = 0; f < F; ++f) {
                float diff = means[(b * F + f) * K + c] - means[(b * F + f) * K + d];
                pd2 += diff * diff;
            }
            float h = fmaxf(2.f * DELTA_DIST - sqrtf(pd2), 0.f);
            total += h * h / (2.f * fnc * (fnc - 1.f) + EPSF) * (1.0f / B);
        }
    }
    red[tid] = total;
    __syncthreads();
    for (int s = 128; s > 0; s >>= 1) {
        if (tid < s) red[tid] += red[tid + s];
        __syncthreads();
    }
    if (tid == 0) out[0] = red[0];
}

extern "C" void kernel_launch(void* const* d_in, const int* in_sizes, int n_in,
                              void* d_out, int out_size, void* d_ws, size_t ws_size,
                              hipStream_t stream) {
    const float* x = (const float*)d_in[0];
    const float* t = (const float*)d_in[1];
    const int* ncl = (const int*)d_in[2];
    float* out = (float*)d_out;

    char* ws = (char*)d_ws;
    float* sums = (float*)ws;
    float* counts = (float*)(ws + OFF_COUNTS);
    float* varsums = (float*)(ws + OFF_VARS);
    float* means = (float*)(ws + OFF_MEANS);
    unsigned char* labels = (unsigned char*)(ws + OFF_LABELS);

    // zero the atomic accumulators (sums, counts, varsums); ws is poisoned 0xAA
    hipMemsetAsync(ws, 0, OFF_MEANS, stream);

    k1_sums<<<B * NCHUNK, 256, 0, stream>>>(x, t, sums, counts, labels);
    k2_means<<<(B * F * K + 255) / 256, 256, 0, stream>>>(sums, counts, ncl, means);
    k3_var<<<B * NCHUNK, 256, 0, stream>>>(x, labels, means, varsums);
    k4_final<<<1, 256, 0, stream>>>(means, counts, varsums, ncl, out);
}

// Round 3
// 315.113 us; speedup vs baseline: 1.0231x; 1.0231x over previous
//
#include <hip/hip_runtime.h>

#define B 8
#define F 16
#define K 24
#define L 147456            // 384*384
#define CHUNK 1024          // pixels per block (256 threads x 4 pixels)
#define NCHUNK (L / CHUNK)  // 144
#define EPSF 1e-8f
#define DELTA_VAR 0.5f
#define DELTA_DIST 1.5f
#define GAMMA 0.001f

typedef float fx4 __attribute__((ext_vector_type(4)));  // native vec for nontemporal builtin

// Workspace layout (bytes):
//   0      : sums    float[B][F][K]   (12288)
//   12288  : counts  float[B][K]      (768)
//   13056  : varsums float[B][K]      (768)
//   13824  : means   float[B][F][K]   (12288)  -> ends at 26112
//   26624  : labels  uint8[B][L]      (1179648) -> total ~1.18 MB
#define OFF_COUNTS 12288
#define OFF_VARS   13056
#define OFF_MEANS  13824
#define OFF_LABELS 26624

// ---------------- Kernel 1: segment sums + counts + label cache ----------------
// MLP-restructured: batch 12 t-loads / 8 x-loads into register arrays so the
// wave keeps many 1KB loads in flight instead of one dependent chain.
__global__ __launch_bounds__(256) void k1_sums(const float* __restrict__ x,
                                               const float* __restrict__ t,
                                               float* __restrict__ sums,
                                               float* __restrict__ counts,
                                               unsigned char* __restrict__ labels) {
    __shared__ float acc[4][F * 25];   // per-wave, stride 25 to spread banks
    __shared__ float cnt[4][K];
    const int tid = threadIdx.x;
    const int w = tid >> 6;

    for (int i = tid; i < 4 * F * 25; i += 256) ((float*)acc)[i] = 0.f;
    for (int i = tid; i < 4 * K; i += 256) ((float*)cnt)[i] = 0.f;
    __syncthreads();

    const int b = blockIdx.x / NCHUNK;
    const int chunk = blockIdx.x % NCHUNK;
    const int l = chunk * CHUNK + tid * 4;

    const fx4* t4 = (const fx4*)t;
    const fx4* x4 = (const fx4*)x;

    // --- labels: t is exactly one-hot fp32. Two batches of 12 in-flight loads.
    // Nontemporal: t is read exactly once across the whole problem — keep it
    // from evicting x out of L3 (k3 re-reads x).
    int lab0 = 0, lab1 = 0, lab2 = 0, lab3 = 0;
    #pragma unroll
    for (int h = 0; h < 2; ++h) {
        fx4 tv[12];
        #pragma unroll
        for (int j = 0; j < 12; ++j)
            tv[j] = __builtin_nontemporal_load(
                &t4[((size_t)(b * K + h * 12 + j) * L + l) >> 2]);
        #pragma unroll
        for (int j = 0; j < 12; ++j) {
            int c = h * 12 + j;
            lab0 += c * (tv[j].x > 0.5f);
            lab1 += c * (tv[j].y > 0.5f);
            lab2 += c * (tv[j].z > 0.5f);
            lab3 += c * (tv[j].w > 0.5f);
        }
    }

    // cache labels for pass 2 (issue early, independent of the x loads)
    *(uchar4*)&labels[(size_t)b * L + l] =
        make_uchar4((unsigned char)lab0, (unsigned char)lab1,
                    (unsigned char)lab2, (unsigned char)lab3);

    // --- accumulate x into per-wave [f][label] sums. Two batches of 8 loads.
    float* a = acc[w];
    #pragma unroll
    for (int h = 0; h < 2; ++h) {
        fx4 xv[8];
        #pragma unroll
        for (int j = 0; j < 8; ++j)
            xv[j] = x4[((size_t)(b * F + h * 8 + j) * L + l) >> 2];
        #pragma unroll
        for (int j = 0; j < 8; ++j) {
            float* af = a + (h * 8 + j) * 25;
            atomicAdd(&af[lab0], xv[j].x);
            atomicAdd(&af[lab1], xv[j].y);
            atomicAdd(&af[lab2], xv[j].z);
            atomicAdd(&af[lab3], xv[j].w);
        }
    }
    atomicAdd(&cnt[w][lab0], 1.f);
    atomicAdd(&cnt[w][lab1], 1.f);
    atomicAdd(&cnt[w][lab2], 1.f);
    atomicAdd(&cnt[w][lab3], 1.f);

    __syncthreads();
    // block reduce 4 wave-copies -> global atomics (3264 distinct addresses)
    for (int i = tid; i < F * K; i += 256) {
        int f = i / K, c = i % K;
        float v = acc[0][f * 25 + c] + acc[1][f * 25 + c] +
                  acc[2][f * 25 + c] + acc[3][f * 25 + c];
        atomicAdd(&sums[(b * F + f) * K + c], v);
    }
    for (int i = tid; i < K; i += 256) {
        float v = cnt[0][i] + cnt[1][i] + cnt[2][i] + cnt[3][i];
        atomicAdd(&counts[b * K + i], v);
    }
}

// ---------------- Kernel 2: finalize means ----------------
__global__ __launch_bounds__(256) void k2_means(const float* __restrict__ sums,
                                                const float* __restrict__ counts,
                                                const int* __restrict__ ncl,
                                                float* __restrict__ means) {
    int idx = blockIdx.x * 256 + threadIdx.x;
    if (idx >= B * F * K) return;
    int b = idx / (F * K);
    int c = idx % K;
    float valid = (c < ncl[b]) ? 1.f : 0.f;
    means[idx] = sums[idx] / (counts[b * K + c] + EPSF) * valid;
}

// ---------------- Kernel 3: per-pixel variance hinge, per-cluster sums ----------------
__global__ __launch_bounds__(256) void k3_var(const float* __restrict__ x,
                                              const unsigned char* __restrict__ labels,
                                              const float* __restrict__ means,
                                              float* __restrict__ varsums) {
    __shared__ float m[F * K];       // this batch's means
    __shared__ float vacc[4][K];
    const int tid = threadIdx.x;
    const int w = tid >> 6;
    const int b = blockIdx.x / NCHUNK;
    const int chunk = blockIdx.x % NCHUNK;
    const int l = chunk * CHUNK + tid * 4;

    // issue label + x loads before the means staging so everything overlaps
    uchar4 lv = *(const uchar4*)&labels[(size_t)b * L + l];

    for (int i = tid; i < F * K; i += 256) m[i] = means[b * F * K + i];
    for (int i = tid; i < 4 * K; i += 256) ((float*)vacc)[i] = 0.f;
    __syncthreads();

    const int lab0 = lv.x, lab1 = lv.y, lab2 = lv.z, lab3 = lv.w;

    float d0 = 0.f, d1 = 0.f, d2 = 0.f, d3 = 0.f;
    const fx4* x4 = (const fx4*)x;
    #pragma unroll
    for (int h = 0; h < 2; ++h) {
        fx4 xv[8];
        #pragma unroll
        for (int j = 0; j < 8; ++j)
            xv[j] = x4[((size_t)(b * F + h * 8 + j) * L + l) >> 2];
        #pragma unroll
        for (int j = 0; j < 8; ++j) {
            int f = h * 8 + j;
            float u0 = xv[j].x - m[f * K + lab0]; d0 += u0 * u0;
            float u1 = xv[j].y - m[f * K + lab1]; d1 += u1 * u1;
            float u2 = xv[j].z - m[f * K + lab2]; d2 += u2 * u2;
            float u3 = xv[j].w - m[f * K + lab3]; d3 += u3 * u3;
        }
    }
    float s0 = fmaxf(sqrtf(d0) - DELTA_VAR, 0.f); s0 *= s0;
    float s1 = fmaxf(sqrtf(d1) - DELTA_VAR, 0.f); s1 *= s1;
    float s2 = fmaxf(sqrtf(d2) - DELTA_VAR, 0.f); s2 *= s2;
    float s3 = fmaxf(sqrtf(d3) - DELTA_VAR, 0.f); s3 *= s3;
    atomicAdd(&vacc[w][lab0], s0);
    atomicAdd(&vacc[w][lab1], s1);
    atomicAdd(&vacc[w][lab2], s2);
    atomicAdd(&vacc[w][lab3], s3);

    __syncthreads();
    for (int i = tid; i < K; i += 256) {
        float v = vacc[0][i] + vacc[1][i] + vacc[2][i] + vacc[3][i];
        atomicAdd(&varsums[b * K + i], v);
    }
}

// ---------------- Kernel 4: combine all three terms -> scalar ----------------
__global__ __launch_bounds__(256) void k4_final(const float* __restrict__ means,
                                                const float* __restrict__ counts,
                                                const float* __restrict__ varsums,
                                                const int* __restrict__ ncl,
                                                float* __restrict__ out) {
    __shared__ float red[256];
    const int tid = threadIdx.x;
    float total = 0.f;
    for (int idx = tid; idx < B * K * K; idx += 256) {
        int b = idx / (K * K);
        int r = idx % (K * K);
        int c = r / K;
        int d = r % K;
        int ncb = ncl[b];
        float fnc = (float)ncb;
        if (d == 0 && c < ncb && ncb > 0) {
            float cv = varsums[b * K + c] / (counts[b * K + c] + EPSF);
            total += cv / (fnc + EPSF) * (1.0f / B);
            float m2 = 0.f;
            #pragma unroll
            for (int f = 0; f < F; ++f) {
                float mv = means[(b * F + f) * K + c];
                m2 += mv * mv;
            }
            total += GAMMA * sqrtf(m2) / fnc * (1.0f / B);
        }
        if (c != d && c < ncb && d < ncb && ncb > 1) {
            float pd2 = 0.f;
            #pragma unroll
            for (int f = 0; f < F; ++f) {
                float diff = means[(b * F + f) * K + c] - means[(b * F + f) * K + d];
                pd2 += diff * diff;
            }
            float h = fmaxf(2.f * DELTA_DIST - sqrtf(pd2), 0.f);
            total += h * h / (2.f * fnc * (fnc - 1.f) + EPSF) * (1.0f / B);
        }
    }
    red[tid] = total;
    __syncthreads();
    for (int s = 128; s > 0; s >>= 1) {
        if (tid < s) red[tid] += red[tid + s];
        __syncthreads();
    }
    if (tid == 0) out[0] = red[0];
}

extern "C" void kernel_launch(void* const* d_in, const int* in_sizes, int n_in,
                              void* d_out, int out_size, void* d_ws, size_t ws_size,
                              hipStream_t stream) {
    const float* x = (const float*)d_in[0];
    const float* t = (const float*)d_in[1];
    const int* ncl = (const int*)d_in[2];
    float* out = (float*)d_out;

    char* ws = (char*)d_ws;
    float* sums = (float*)ws;
    float* counts = (float*)(ws + OFF_COUNTS);
    float* varsums = (float*)(ws + OFF_VARS);
    float* means = (float*)(ws + OFF_MEANS);
    unsigned char* labels = (unsigned char*)(ws + OFF_LABELS);

    (void)hipMemsetAsync(ws, 0, OFF_MEANS, stream);

    k1_sums<<<B * NCHUNK, 256, 0, stream>>>(x, t, sums, counts, labels);
    k2_means<<<(B * F * K + 255) / 256, 256, 0, stream>>>(sums, counts, ncl, means);
    k3_var<<<B * NCHUNK, 256, 0, stream>>>(x, labels, means, varsums);
    k4_final<<<1, 256, 0, stream>>>(means, counts, varsums, ncl, out);
}